// Round 4
// baseline (4326.270 us; speedup 1.0000x reference)
//
#include <hip/hip_runtime.h>
#include <hip/hip_bf16.h>

typedef _Float16 f16;
typedef f16 f16x8 __attribute__((ext_vector_type(8)));
typedef f16 f16x4 __attribute__((ext_vector_type(4)));
typedef float f32x4 __attribute__((ext_vector_type(4)));

#define MFMA16(a,b,c) __builtin_amdgcn_mfma_f32_16x16x32_f16(a,b,c,0,0,0)

// problem sizes
#define SS 128   // sentence length
#define HH 256   // hidden
#define NSEQ 512 // B*P sequences

// workspace byte offsets
#define WS_E16   (0)
#define WS_W16   (33554432)
#define WS_SEN   (37224448)
#define WS_U1    (37748736)
#define WS_H1    (38797312)
#define WS_LENS  (38813696)
#define WS_NEED  (38815744)

// f16 weight pool element offsets
#define OFF_WIH0F 0
#define OFF_WHH0F 262144
#define OFF_WIH0B 524288
#define OFF_WHH0B 786432
#define OFF_WIH1  1048576
#define OFF_WHH1  1572864

__device__ __forceinline__ float fsig(float x){
  x = fminf(fmaxf(x, -30.f), 30.f);
  float e = __expf(-x);
  return __builtin_amdgcn_rcpf(1.f + e);
}
__device__ __forceinline__ float ftanh(float x){
  x = fminf(fmaxf(x, -15.f), 15.f);
  float e = __expf(2.f * x);
  return (e - 1.f) * __builtin_amdgcn_rcpf(e + 1.f);
}

// ---------------- weight f32 -> f16 convert ----------------
__global__ __launch_bounds__(256) void cvt_kernel(const float* __restrict__ src,
                                                  f16* __restrict__ dst, int n4){
  int i = blockIdx.x * 256 + threadIdx.x;
  if (i < n4){
    const float4 v = *(const float4*)(src + (size_t)i * 4);
    f16x4 o; o[0] = (f16)v.x; o[1] = (f16)v.y; o[2] = (f16)v.z; o[3] = (f16)v.w;
    *(f16x4*)(dst + (size_t)i * 4) = o;
  }
}

// ---------------- embedding gather -> e16[t][s][k] ----------------
__global__ __launch_bounds__(256) void gather_kernel(const int* __restrict__ x,
                                                     const float* __restrict__ emb,
                                                     f16* __restrict__ e16){
  const int tid = threadIdx.x;
  const int row = blockIdx.x * 4 + (tid >> 6);  // row = t*512 + s
  const int l = tid & 63;
  const int t = row >> 9, s = row & 511;
  const int token = x[s * SS + t];
  const float4 v = *(const float4*)(emb + (size_t)token * HH + l * 4);
  f16x4 o; o[0] = (f16)v.x; o[1] = (f16)v.y; o[2] = (f16)v.z; o[3] = (f16)v.w;
  *(f16x4*)(e16 + (size_t)row * HH + l * 4) = o;
}

// ---------------- sequence lengths from mask ----------------
__global__ __launch_bounds__(64) void lens_kernel(const int* __restrict__ xm,
                                                  int* __restrict__ lens){
  const int s = blockIdx.x, l = threadIdx.x;
  const int v0 = (xm[s * SS + l] == 0) ? 1 : 0;
  const int v1 = (xm[s * SS + 64 + l] == 0) ? 1 : 0;
  unsigned long long b0 = __ballot(v0), b1 = __ballot(v1);
  if (l == 0) lens[s] = __popcll(b0) + __popcll(b1);
}

// ---------------- layer-0 bidirectional LSTM (fused input GEMM) ----------------
// 64 blocks x 512 threads. block = (dir, 16 sequences). wave w owns hidden cols [w*32, w*32+32).
__global__ __launch_bounds__(512, 2) void lstm0_kernel(
    const f16* __restrict__ e16, const f16* __restrict__ w16,
    const float* __restrict__ b0f, const float* __restrict__ b0b,
    const int* __restrict__ lens, f16* __restrict__ sen16)
{
  __shared__ f16 hlds[16 * 264];
  const int tid = threadIdx.x;
  const int w = tid >> 6, l = tid & 63, lrow = l & 15, lgrp = l >> 4;
  const int wg = blockIdx.x, dir = wg >> 5, sb = (wg & 31) * 16;
  const f16* __restrict__ Wih = w16 + (dir ? OFF_WIH0B : OFF_WIH0F);
  const f16* __restrict__ Whh = w16 + (dir ? OFF_WHH0B : OFF_WHH0F);
  const float* __restrict__ bias = dir ? b0b : b0f;

  for (int i = tid; i < 16 * 264; i += 512) hlds[i] = (f16)0.f;

  int len4[4];
  #pragma unroll
  for (int r = 0; r < 4; ++r) len4[r] = lens[sb + lgrp * 4 + r];

  float bs_[4][2];
  #pragma unroll
  for (int g = 0; g < 4; ++g)
    #pragma unroll
    for (int p = 0; p < 2; ++p)
      bs_[g][p] = bias[g * 256 + w * 32 + p * 16 + lrow];

  float c[2][4] = {}, hreg[2][4] = {};
  __syncthreads();

  for (int tt = 0; tt < SS; ++tt){
    const int t = dir ? (SS - 1 - tt) : tt;
    f16x8 Ah[8], Ae[8];
    #pragma unroll
    for (int kk = 0; kk < 8; ++kk)
      Ah[kk] = *(const f16x8*)&hlds[lrow * 264 + kk * 32 + lgrp * 8];
    const f16* ep = e16 + ((size_t)t * NSEQ + sb + lrow) * HH + lgrp * 8;
    #pragma unroll
    for (int kk = 0; kk < 8; ++kk)
      Ae[kk] = *(const f16x8*)(ep + kk * 32);
    __syncthreads();   // all h reads done

    #pragma unroll
    for (int p = 0; p < 2; ++p){
      f32x4 a0 = {0.f,0.f,0.f,0.f}, a1 = {0.f,0.f,0.f,0.f};
      f32x4 a2 = {0.f,0.f,0.f,0.f}, a3 = {0.f,0.f,0.f,0.f};
      const int cb = w * 32 + p * 16 + lrow;
      const f16* wh = Whh + (size_t)cb * HH + lgrp * 8;
      const f16* wi = Wih + (size_t)cb * HH + lgrp * 8;
      #pragma unroll
      for (int kk = 0; kk < 8; ++kk){
        f16x8 q0 = *(const f16x8*)(wh + kk * 32);
        f16x8 q1 = *(const f16x8*)(wh + 65536 + kk * 32);
        f16x8 q2 = *(const f16x8*)(wh + 131072 + kk * 32);
        f16x8 q3 = *(const f16x8*)(wh + 196608 + kk * 32);
        a0 = MFMA16(Ah[kk], q0, a0);
        a1 = MFMA16(Ah[kk], q1, a1);
        a2 = MFMA16(Ah[kk], q2, a2);
        a3 = MFMA16(Ah[kk], q3, a3);
      }
      #pragma unroll
      for (int kk = 0; kk < 8; ++kk){
        f16x8 q0 = *(const f16x8*)(wi + kk * 32);
        f16x8 q1 = *(const f16x8*)(wi + 65536 + kk * 32);
        f16x8 q2 = *(const f16x8*)(wi + 131072 + kk * 32);
        f16x8 q3 = *(const f16x8*)(wi + 196608 + kk * 32);
        a0 = MFMA16(Ae[kk], q0, a0);
        a1 = MFMA16(Ae[kk], q1, a1);
        a2 = MFMA16(Ae[kk], q2, a2);
        a3 = MFMA16(Ae[kk], q3, a3);
      }
      #pragma unroll
      for (int r = 0; r < 4; ++r){
        const float iv = fsig(a0[r] + bs_[0][p]);
        const float fv = fsig(a1[r] + bs_[1][p]);
        const float gv = ftanh(a2[r] + bs_[2][p]);
        const float ov = fsig(a3[r] + bs_[3][p]);
        const float cn = fv * c[p][r] + iv * gv;
        const float hn = ov * ftanh(cn);
        const bool v = (t < len4[r]);
        c[p][r]    = v ? cn : c[p][r];
        hreg[p][r] = v ? hn : hreg[p][r];
      }
    }
    #pragma unroll
    for (int p = 0; p < 2; ++p)
      #pragma unroll
      for (int r = 0; r < 4; ++r)
        hlds[(lgrp * 4 + r) * 264 + w * 32 + p * 16 + lrow] = (f16)hreg[p][r];
    __syncthreads(); // h writes visible
  }

  #pragma unroll
  for (int p = 0; p < 2; ++p)
    #pragma unroll
    for (int r = 0; r < 4; ++r){
      const int s = sb + lgrp * 4 + r;
      const int brow = s >> 5, prow = s & 31;
      sen16[(size_t)(prow * 16 + brow) * 512 + dir * 256 + w * 32 + p * 16 + lrow]
        = (f16)hreg[p][r];
    }
}

// ---------------- layer-1 input GEMM: U1[p][gcol][b] = sen16[p] @ Wih1^T ----------------
__global__ __launch_bounds__(256, 2) void u1_gemm_kernel(
    const f16* __restrict__ sen16, const f16* __restrict__ w16, f16* __restrict__ U1)
{
  const int tid = threadIdx.x;
  const int w = tid >> 6, l = tid & 63, lrow = l & 15, lgrp = l >> 4;
  const int p = blockIdx.x;
  const f16* __restrict__ Wih1 = w16 + OFF_WIH1;

  f16x8 A[16];
  #pragma unroll
  for (int kb = 0; kb < 16; ++kb)
    A[kb] = *(const f16x8*)&sen16[(size_t)(p * 16 + lrow) * 512 + kb * 32 + lgrp * 8];

  for (int tile = 0; tile < 16; ++tile){
    const int col = (w * 16 + tile) * 16 + lrow;
    const f16* wp = Wih1 + (size_t)col * 512 + lgrp * 8;
    f32x4 acc = {0.f,0.f,0.f,0.f};
    #pragma unroll
    for (int kb = 0; kb < 16; ++kb){
      f16x8 bfrag = *(const f16x8*)(wp + kb * 32);
      acc = MFMA16(A[kb], bfrag, acc);
    }
    f16x4 o4;
    #pragma unroll
    for (int r = 0; r < 4; ++r) o4[r] = (f16)acc[r];
    *(f16x4*)&U1[((size_t)p * 1024 + col) * 16 + lgrp * 4] = o4;
  }
}

// ---------------- layer-1 LSTM over paragraph positions ----------------
__global__ __launch_bounds__(512, 2) void lstm1_kernel(
    const f16* __restrict__ w16, const f16* __restrict__ U1,
    const float* __restrict__ b1, float* __restrict__ h1)
{
  __shared__ f16 hlds[16 * 264];
  const int tid = threadIdx.x;
  const int w = tid >> 6, l = tid & 63, lrow = l & 15, lgrp = l >> 4;
  const f16* __restrict__ Whh = w16 + OFF_WHH1;

  for (int i = tid; i < 16 * 264; i += 512) hlds[i] = (f16)0.f;
  float bs_[4][2];
  #pragma unroll
  for (int g = 0; g < 4; ++g)
    #pragma unroll
    for (int p = 0; p < 2; ++p)
      bs_[g][p] = b1[g * 256 + w * 32 + p * 16 + lrow];
  float c[2][4] = {}, hreg[2][4] = {};
  __syncthreads();

  for (int pt = 0; pt < 32; ++pt){
    f16x8 Ah[8];
    #pragma unroll
    for (int kk = 0; kk < 8; ++kk)
      Ah[kk] = *(const f16x8*)&hlds[lrow * 264 + kk * 32 + lgrp * 8];
    __syncthreads();

    #pragma unroll
    for (int p = 0; p < 2; ++p){
      f32x4 a0 = {0.f,0.f,0.f,0.f}, a1 = {0.f,0.f,0.f,0.f};
      f32x4 a2 = {0.f,0.f,0.f,0.f}, a3 = {0.f,0.f,0.f,0.f};
      const int cb = w * 32 + p * 16 + lrow;
      const f16* wh = Whh + (size_t)cb * HH + lgrp * 8;
      #pragma unroll
      for (int kk = 0; kk < 8; ++kk){
        f16x8 q0 = *(const f16x8*)(wh + kk * 32);
        f16x8 q1 = *(const f16x8*)(wh + 65536 + kk * 32);
        f16x8 q2 = *(const f16x8*)(wh + 131072 + kk * 32);
        f16x8 q3 = *(const f16x8*)(wh + 196608 + kk * 32);
        a0 = MFMA16(Ah[kk], q0, a0);
        a1 = MFMA16(Ah[kk], q1, a1);
        a2 = MFMA16(Ah[kk], q2, a2);
        a3 = MFMA16(Ah[kk], q3, a3);
      }
      f16x4 u[4];
      #pragma unroll
      for (int g = 0; g < 4; ++g)
        u[g] = *(const f16x4*)&U1[((size_t)pt * 1024 + g * 256 + cb) * 16 + lgrp * 4];
      #pragma unroll
      for (int r = 0; r < 4; ++r){
        const float iv = fsig (a0[r] + (float)u[0][r] + bs_[0][p]);
        const float fv = fsig (a1[r] + (float)u[1][r] + bs_[1][p]);
        const float gv = ftanh(a2[r] + (float)u[2][r] + bs_[2][p]);
        const float ov = fsig (a3[r] + (float)u[3][r] + bs_[3][p]);
        const float cn = fv * c[p][r] + iv * gv;
        c[p][r] = cn;
        hreg[p][r] = ov * ftanh(cn);
      }
    }
    #pragma unroll
    for (int p = 0; p < 2; ++p)
      #pragma unroll
      for (int r = 0; r < 4; ++r)
        hlds[(lgrp * 4 + r) * 264 + w * 32 + p * 16 + lrow] = (f16)hreg[p][r];
    __syncthreads();
  }

  #pragma unroll
  for (int p = 0; p < 2; ++p)
    #pragma unroll
    for (int r = 0; r < 4; ++r)
      h1[(lgrp * 4 + r) * 256 + w * 32 + p * 16 + lrow] = hreg[p][r];
}

// ---------------- final FC: out[b][o] = h1[b] . Wfc[o] + bfc[o] ----------------
__global__ __launch_bounds__(256) void fc_kernel(const float* __restrict__ h1,
                                                 const float* __restrict__ Wfc,
                                                 const float* __restrict__ bfc,
                                                 float* __restrict__ out){
  __shared__ float hl[16 * 256];
  const int tid = threadIdx.x;
  for (int i = tid; i < 4096; i += 256) hl[i] = h1[i];
  __syncthreads();
  const int o = tid & 127, half = tid >> 7;
  float acc[8];
  #pragma unroll
  for (int i = 0; i < 8; ++i) acc[i] = bfc[o];
  const float* wp = Wfc + (size_t)o * 256;
  for (int j = 0; j < 256; ++j){
    const float wv = wp[j];
    #pragma unroll
    for (int i = 0; i < 8; ++i) acc[i] += wv * hl[(half * 8 + i) * 256 + j];
  }
  #pragma unroll
  for (int i = 0; i < 8; ++i) out[(half * 8 + i) * 128 + o] = acc[i];
}

extern "C" void kernel_launch(void* const* d_in, const int* in_sizes, int n_in,
                              void* d_out, int out_size, void* d_ws, size_t ws_size,
                              hipStream_t stream) {
  if (ws_size < (size_t)WS_NEED) return;  // workspace too small (constant per-session)

  const int*   x     = (const int*)  d_in[0];
  const int*   xm    = (const int*)  d_in[1];
  const float* emb   = (const float*)d_in[2];
  const float* Wih0f = (const float*)d_in[3];
  const float* Whh0f = (const float*)d_in[4];
  const float* b0f   = (const float*)d_in[5];
  const float* Wih0b = (const float*)d_in[6];
  const float* Whh0b = (const float*)d_in[7];
  const float* b0b   = (const float*)d_in[8];
  const float* Wih1  = (const float*)d_in[9];
  const float* Whh1  = (const float*)d_in[10];
  const float* b1    = (const float*)d_in[11];
  const float* Wfc   = (const float*)d_in[12];
  const float* bfc   = (const float*)d_in[13];
  float* out = (float*)d_out;
  char*  ws  = (char*)d_ws;

  f16*   e16   = (f16*)(ws + WS_E16);
  f16*   w16   = (f16*)(ws + WS_W16);
  f16*   sen16 = (f16*)(ws + WS_SEN);
  f16*   U1    = (f16*)(ws + WS_U1);
  float* h1    = (float*)(ws + WS_H1);
  int*   lens  = (int*)(ws + WS_LENS);

  // weight conversions (f32 -> f16)
  cvt_kernel<<<256, 256, 0, stream>>>(Wih0f, w16 + OFF_WIH0F, 65536);
  cvt_kernel<<<256, 256, 0, stream>>>(Whh0f, w16 + OFF_WHH0F, 65536);
  cvt_kernel<<<256, 256, 0, stream>>>(Wih0b, w16 + OFF_WIH0B, 65536);
  cvt_kernel<<<256, 256, 0, stream>>>(Whh0b, w16 + OFF_WHH0B, 65536);
  cvt_kernel<<<512, 256, 0, stream>>>(Wih1,  w16 + OFF_WIH1, 131072);
  cvt_kernel<<<256, 256, 0, stream>>>(Whh1,  w16 + OFF_WHH1,  65536);

  gather_kernel<<<16384, 256, 0, stream>>>(x, emb, e16);
  lens_kernel<<<512, 64, 0, stream>>>(xm, lens);

  lstm0_kernel<<<64, 512, 0, stream>>>(e16, w16, b0f, b0b, lens, sen16);
  u1_gemm_kernel<<<32, 256, 0, stream>>>(sen16, w16, U1);
  lstm1_kernel<<<1, 512, 0, stream>>>(w16, U1, b1, h1);
  fc_kernel<<<1, 256, 0, stream>>>(h1, Wfc, bfc, out);
}